// Round 9
// baseline (36.986 us; speedup 1.0000x reference)
//
#include <hip/hip_runtime.h>
#include <hip/hip_bf16.h>

#define Bsz 2048
#define Dim 128
#define Nrows 4096

typedef float f32x4 __attribute__((ext_vector_type(4)));
typedef __bf16 bf16x8 __attribute__((ext_vector_type(8)));

#define GLD_LDS16(gp, lp)                                                        \
    __builtin_amdgcn_global_load_lds(                                            \
        (const __attribute__((address_space(1))) void*)(gp),                     \
        (__attribute__((address_space(3))) void*)(lp), 16, 0, 0)

// ws layout:
//   U    @ 0      : 4096*128*2 = 1 MiB (bf16 normalized rows)
//   part @ 1 MiB  : 4096*64*4  = 1 MiB (per (row,strip64) sum exp(S-2), diag excl)
//   rs1p @ 2 MiB  : 1 MiB (per (row,strip64) sum lab_j*S/2)
//   rsap @ 3 MiB  : 1 MiB (per (row,strip64) sum S/2)
//   dpv  @ 4 MiB  : 16 KiB (S(i,partner)/2)
//   rowC @ 4M+16K : 256*4 ; rowU @ +1K ; c1 @ +2K

// K1: normalize [z; z_aug] -> bf16 U (16 rows/block); block 0 counts labels==1
__global__ __launch_bounds__(256) void k_norm(const float* __restrict__ z,
                                              const float* __restrict__ za,
                                              const long long* __restrict__ labels,
                                              __bf16* __restrict__ U,
                                              int* __restrict__ c1out) {
    const int wid = threadIdx.x >> 6, lane = threadIdx.x & 63;
    #pragma unroll
    for (int pass = 0; pass < 4; pass++) {
        const int r = blockIdx.x * 16 + pass * 4 + wid;
        const float* src = (r < Bsz) ? (z + (size_t)r * Dim) : (za + (size_t)(r - Bsz) * Dim);
        float2 x = reinterpret_cast<const float2*>(src)[lane];
        float ss = x.x * x.x + x.y * x.y;
        #pragma unroll
        for (int m = 1; m < 64; m <<= 1) ss += __shfl_xor(ss, m);
        const float sc = 1.0f / fmaxf(sqrtf(ss), 1e-12f);
        __bf16* dst = U + (size_t)r * Dim + 2 * lane;
        dst[0] = (__bf16)(x.x * sc);
        dst[1] = (__bf16)(x.y * sc);
    }
    if (blockIdx.x == 0) {
        __shared__ int ci[256];
        const int t = threadIdx.x;
        int c = 0;
        #pragma unroll
        for (int k = 0; k < 8; k++) c += (int)labels[t * 8 + k];
        ci[t] = c;
        __syncthreads();
        for (int s = 128; s > 0; s >>= 1) {
            if (t < s) ci[t] += ci[t + s];
            __syncthreads();
        }
        if (t == 0) c1out[0] = ci[0];
    }
}

// K2: 128x128 Gram tile, 1024 blocks x 256 thr, 4 blocks/CU.
// i-side b-frags: direct global reads (issued first, latency hidden by staging).
// j-panel: global_load_lds width=16 into 32 KB LDS, chunk-XOR swizzle applied on
// the GLOBAL SOURCE address (LDS dest linear); reads use the same XOR.
// Swapped operands D[j][i] = mfma(A=U_j, B=U_i): i = l15 lane-local -> scalar
// accumulators; j collapses in-register + 2 shuffles. One barrier total.
__global__ __launch_bounds__(256, 4) void k_gram(const __bf16* __restrict__ U,
                                                 const long long* __restrict__ labels,
                                                 float* __restrict__ part,
                                                 float* __restrict__ rs1p,
                                                 float* __restrict__ rsap,
                                                 float* __restrict__ dpv) {
    __shared__ __bf16 Aj[128 * 128];   // [row][16 chunks of 8 bf16], chunk pre-swizzled

    const int iblk = blockIdx.x >> 5, jblk = blockIdx.x & 31;
    const int ibase = iblk * 128, jbase = jblk * 128;
    const int w = threadIdx.x >> 6, lane = threadIdx.x & 63;
    const int wi = w & 1, wj = w >> 1;
    const int l15 = lane & 15, l4 = lane >> 4;

    // ---- i-side B fragments: direct global (read once per wave), issue FIRST
    bf16x8 b[4][4];
    #pragma unroll
    for (int bt = 0; bt < 4; bt++)
        #pragma unroll
        for (int ks = 0; ks < 4; ks++)
            b[bt][ks] = *reinterpret_cast<const bf16x8*>(
                U + (size_t)(ibase + wi * 64 + bt * 16 + l15) * Dim + (ks * 4 + l4) * 8);

    // ---- stage j-panel: 8 x global_load_lds (1 KB/inst), source pre-swizzled
    {
        const int c = lane & 15, rsub = lane >> 4;
        #pragma unroll
        for (int it = 0; it < 8; it++) {
            const int rl = w * 32 + it * 4 + rsub;              // local row 0..127
            const __bf16* src = U + (size_t)(jbase + rl) * Dim + ((c ^ (rl & 7)) * 8);
            GLD_LDS16(src, Aj + (size_t)(w * 32 + it * 4) * 128);
        }
    }

    // label bitmask for this wave's 64 j-cols (overlaps staging)
    const unsigned long long lmask =
        __ballot(labels[(jbase + wj * 64 + lane) & (Bsz - 1)] == 1);

    __syncthreads();   // drains vmcnt (global_load_lds) + lgkm

    float dsum[4] = {0.f, 0.f, 0.f, 0.f};
    float r1s[4]  = {0.f, 0.f, 0.f, 0.f};
    float ras[4]  = {0.f, 0.f, 0.f, 0.f};
    const float KE1 = 2.8853900817779268f;    // 2*log2(e)
    const float KE0 = -2.8853900817779268f;

    #pragma unroll
    for (int at = 0; at < 4; at++) {
        const int rlb = wj * 64 + at * 16 + l15;   // local j-row this lane reads
        bf16x8 a[4];
        #pragma unroll
        for (int ks = 0; ks < 4; ks++)
            a[ks] = *reinterpret_cast<const bf16x8*>(
                Aj + (size_t)rlb * 128 + (((ks * 4 + l4) ^ (rlb & 7)) * 8));
        float labq[4];
        #pragma unroll
        for (int q = 0; q < 4; q++)
            labq[q] = (float)((lmask >> (at * 16 + l4 * 4 + q)) & 1ull);
        const int jt = jbase + wj * 64 + at * 16;

        #pragma unroll
        for (int bt = 0; bt < 4; bt++) {
            f32x4 acc = {0.f, 0.f, 0.f, 0.f};
            #pragma unroll
            for (int ks = 0; ks < 4; ks++)
                acc = __builtin_amdgcn_mfma_f32_16x16x32_bf16(a[ks], b[bt][ks], acc, 0, 0, 0);
            const int itl = ibase + wi * 64 + bt * 16;
            const bool dg = (jt == itl);             // tile holds diagonal
            const bool pg = (jt == (itl ^ 2048));    // tile holds partner cols
            #pragma unroll
            for (int q = 0; q < 4; q++) {
                float av = acc[q];                    // S[j][i]/2 == S[i][j]/2
                const bool sel = (l15 == l4 * 4 + q);
                if (pg && sel) dpv[itl + l15] = av;   // S(i, partner)/2
                float e = exp2f(fmaf(av, KE1, KE0));  // exp(S - 2)
                if (dg && sel) { e = 0.f; av = 0.f; } // exclude j == i
                dsum[bt] += e;
                ras[bt] += av;
                r1s[bt] = fmaf(labq[q], av, r1s[bt]);
            }
        }
    }

    // ---- collapse the 4 l4-groups (j-partition); i = l15 stays lane-local.
    // Strip index = jblk*2 + wj (64-wide strips); waves write disjoint slots.
    const int strip = jblk * 2 + wj;
    #pragma unroll
    for (int bt = 0; bt < 4; bt++) {
        float v0 = dsum[bt], v1 = r1s[bt], v2 = ras[bt];
        v0 += __shfl_xor(v0, 16); v0 += __shfl_xor(v0, 32);
        v1 += __shfl_xor(v1, 16); v1 += __shfl_xor(v1, 32);
        v2 += __shfl_xor(v2, 16); v2 += __shfl_xor(v2, 32);
        if (l4 == 0) {
            const int row = ibase + wi * 64 + bt * 16 + l15;
            part[row * 64 + strip] = v0;
            rs1p[row * 64 + strip] = v1;
            rsap[row * 64 + strip] = v2;
        }
    }
}

// K3: 256 blocks x 256 thr; wave = 4 rows. 64-strip reduce + loss -> block partials.
__global__ __launch_bounds__(256) void k_row(const long long* __restrict__ labels,
                                             const int* __restrict__ c1p,
                                             const float* __restrict__ part,
                                             const float* __restrict__ rs1p,
                                             const float* __restrict__ rsap,
                                             const float* __restrict__ dpv,
                                             float* __restrict__ rowC,
                                             float* __restrict__ rowU) {
    const int wid = threadIdx.x >> 6, lane = threadIdx.x & 63;
    const int c1 = *c1p;
    float cs = 0.f, us = 0.f;
    #pragma unroll
    for (int rr = 0; rr < 4; rr++) {
        const int i = blockIdx.x * 16 + wid * 4 + rr;
        float dn = part[i * 64 + lane];
        float v1 = rs1p[i * 64 + lane];
        float va = rsap[i * 64 + lane];
        #pragma unroll
        for (int m = 1; m < 64; m <<= 1) {
            dn += __shfl_xor(dn, m);
            v1 += __shfl_xor(v1, m);
            va += __shfl_xor(va, m);
        }
        if (lane == 0) {
            const long long lb = labels[i & (Bsz - 1)];
            const float lnD = logf(dn) + 2.0f;        // lse over j != i (row max = 2)
            const float uns = lnD - 2.0f * dpv[i];    // pos = S(i, partner)
            const float cnt = 2.f * (float)((lb == 1) ? c1 : (Bsz - c1));
            const float sumeq = 2.f * ((lb == 1) ? v1 : (va - v1));
            const float sup = lnD - sumeq / (cnt - 1.f);
            cs += (lb == 1) ? sup : uns;
            us += uns;
        }
    }
    __shared__ float wcs[4], wus[4];
    if (lane == 0) { wcs[wid] = cs; wus[wid] = us; }
    __syncthreads();
    if (threadIdx.x == 0) {
        rowC[blockIdx.x] = wcs[0] + wcs[1] + wcs[2] + wcs[3];
        rowU[blockIdx.x] = wus[0] + wus[1] + wus[2] + wus[3];
    }
}

// K4: combine 256 block results -> scalar loss
__global__ __launch_bounds__(256) void k_comb(const float* __restrict__ rowC,
                                              const float* __restrict__ rowU,
                                              const int* __restrict__ c1p,
                                              float* __restrict__ out) {
    __shared__ float sc[256], su[256];
    const int t = threadIdx.x;
    sc[t] = rowC[t];
    su[t] = rowU[t];
    __syncthreads();
    for (int s = 128; s > 0; s >>= 1) {
        if (t < s) { sc[t] += sc[t + s]; su[t] += su[t + s]; }
        __syncthreads();
    }
    if (t == 0) out[0] = ((*c1p > 0) ? sc[0] : su[0]) / (float)Nrows;
}

extern "C" void kernel_launch(void* const* d_in, const int* in_sizes, int n_in,
                              void* d_out, int out_size, void* d_ws, size_t ws_size,
                              hipStream_t stream) {
    const float* z  = (const float*)d_in[0];
    const float* za = (const float*)d_in[1];
    const long long* labels = (const long long*)d_in[2];

    char* ws = (char*)d_ws;
    __bf16* U    = (__bf16*)(ws);
    float*  part = (float*)(ws + (1u << 20));
    float*  rs1p = (float*)(ws + (2u << 20));
    float*  rsap = (float*)(ws + (3u << 20));
    float*  dpv  = (float*)(ws + (4u << 20));
    float*  rowC = (float*)(ws + (4u << 20) + (16u << 10));
    float*  rowU = (float*)(ws + (4u << 20) + (17u << 10));
    int*    c1   = (int*)  (ws + (4u << 20) + (18u << 10));
    float*  out  = (float*)d_out;

    hipLaunchKernelGGL(k_norm, dim3(256),  dim3(256), 0, stream, z, za, labels, U, c1);
    hipLaunchKernelGGL(k_gram, dim3(1024), dim3(256), 0, stream, U, labels, part, rs1p, rsap, dpv);
    hipLaunchKernelGGL(k_row,  dim3(256),  dim3(256), 0, stream, labels, c1, part, rs1p, rsap, dpv, rowC, rowU);
    hipLaunchKernelGGL(k_comb, dim3(1),    dim3(256), 0, stream, rowC, rowU, c1, out);
}

// Round 10
// 34.230 us; speedup vs baseline: 1.0805x; 1.0805x over previous
//
#include <hip/hip_runtime.h>
#include <hip/hip_bf16.h>

#define Bsz 2048
#define Dim 128
#define Nrows 4096

typedef float f32x4 __attribute__((ext_vector_type(4)));
typedef __bf16 bf16x8 __attribute__((ext_vector_type(8)));

#define GLD_LDS16(gp, lp)                                                        \
    __builtin_amdgcn_global_load_lds(                                            \
        (const __attribute__((address_space(1))) void*)(gp),                     \
        (__attribute__((address_space(3))) void*)(lp), 16, 0, 0)

// ws layout:
//   U     @ 0           : 4096*128*2 = 1 MiB (bf16 normalized rows)
//   part  @ 1 MiB       : 4096*64*4  = 1 MiB (per (row,strip64) sum exp(S-2), diag excl)
//   w1p   @ 2 MiB       : 256*128*4 = 128 KiB (block partials of sum lab_j*u_j)
//   wallp @ 2 MiB+128K  : 128 KiB (block partials of sum u_j)
//   w1    @ 2 MiB+256K  : 512 B ; wall @ +512 B ; c1 @ +1 KiB
//   rowC  @ 2 MiB+257K  : 1 KiB ; rowU @ +1 KiB

// K1: normalize [z; z_aug] -> bf16 U; per-block partials of w1/wall; block 0: c1
__global__ __launch_bounds__(256) void k_norm(const float* __restrict__ z,
                                              const float* __restrict__ za,
                                              const long long* __restrict__ labels,
                                              __bf16* __restrict__ U,
                                              float* __restrict__ w1p,
                                              float* __restrict__ wallp,
                                              int* __restrict__ c1out) {
    const int wid = threadIdx.x >> 6, lane = threadIdx.x & 63;
    __shared__ float s1[4][128];
    __shared__ float s0[4][128];
    float a1x = 0.f, a1y = 0.f, a0x = 0.f, a0y = 0.f;
    #pragma unroll
    for (int pass = 0; pass < 4; pass++) {
        const int r = blockIdx.x * 16 + pass * 4 + wid;
        const float* src = (r < Bsz) ? (z + (size_t)r * Dim) : (za + (size_t)(r - Bsz) * Dim);
        float2 x = reinterpret_cast<const float2*>(src)[lane];
        float ss = x.x * x.x + x.y * x.y;
        #pragma unroll
        for (int m = 1; m < 64; m <<= 1) ss += __shfl_xor(ss, m);
        const float sc = 1.0f / fmaxf(sqrtf(ss), 1e-12f);
        const float u0 = x.x * sc, u1 = x.y * sc;
        __bf16* dst = U + (size_t)r * Dim + 2 * lane;
        dst[0] = (__bf16)u0;
        dst[1] = (__bf16)u1;
        const float lf = (labels[r & (Bsz - 1)] == 1) ? 1.f : 0.f;
        a0x += u0; a0y += u1;
        a1x = fmaf(lf, u0, a1x); a1y = fmaf(lf, u1, a1y);
    }
    s1[wid][2 * lane] = a1x; s1[wid][2 * lane + 1] = a1y;
    s0[wid][2 * lane] = a0x; s0[wid][2 * lane + 1] = a0y;
    __syncthreads();
    const int t = threadIdx.x;
    if (t < 128) {
        w1p[blockIdx.x * 128 + t]   = s1[0][t] + s1[1][t] + s1[2][t] + s1[3][t];
        wallp[blockIdx.x * 128 + t] = s0[0][t] + s0[1][t] + s0[2][t] + s0[3][t];
    }
    if (blockIdx.x == 0) {
        __shared__ int ci[256];
        int c = 0;
        #pragma unroll
        for (int k = 0; k < 8; k++) c += (int)labels[t * 8 + k];
        ci[t] = c;
        __syncthreads();
        for (int s = 128; s > 0; s >>= 1) {
            if (t < s) ci[t] += ci[t + s];
            __syncthreads();
        }
        if (t == 0) c1out[0] = ci[0];
    }
}

// K2: 1024 Gram blocks (128x128 tile, both panels GLD_LDS-staged into 64 KB LDS,
// source-side XOR swizzle, 2 blocks/CU) + 1 side block (#1024) reducing w1p/wallp.
// Swapped operands D[j][i]: i = l15 lane-local -> scalar exp-accumulator only
// (rank-1 algebra moved the masked sums out of the epilogue). One barrier.
__global__ __launch_bounds__(256, 2) void k_gram(const __bf16* __restrict__ U,
                                                 const float* __restrict__ w1p,
                                                 const float* __restrict__ wallp,
                                                 float* __restrict__ part,
                                                 float* __restrict__ w1,
                                                 float* __restrict__ wall) {
    if (blockIdx.x == 1024) {   // side block: reduce 256 w-partials -> w1/wall
        const int t = threadIdx.x;
        const int d = t & 127;
        const float* src = (t < 128) ? w1p : wallp;
        float acc = 0.f;
        #pragma unroll 8
        for (int k = 0; k < 256; k++) acc += src[k * 128 + d];
        if (t < 128) w1[d] = acc; else wall[d] = acc;
        return;
    }

    __shared__ __bf16 Ai[128 * 128];   // i-panel: [row][16 chunks of 8 bf16]
    __shared__ __bf16 Aj[128 * 128];   // j-panel, same layout; chunks pre-swizzled

    const int iblk = blockIdx.x >> 5, jblk = blockIdx.x & 31;
    const int ibase = iblk * 128, jbase = jblk * 128;
    const int w = threadIdx.x >> 6, lane = threadIdx.x & 63;
    const int wi = w & 1, wj = w >> 1;
    const int l15 = lane & 15, l4 = lane >> 4;

    // ---- stage both panels: LDS dest linear, global source pre-swizzled
    {
        const int c = lane & 15, rsub = lane >> 4;
        #pragma unroll
        for (int it = 0; it < 8; it++) {
            const int rl = w * 32 + it * 4 + rsub;   // local row 0..127
            const int soff = (c ^ (rl & 7)) * 8;
            GLD_LDS16(U + (size_t)(ibase + rl) * Dim + soff, Ai + (size_t)(w * 32 + it * 4) * 128);
            GLD_LDS16(U + (size_t)(jbase + rl) * Dim + soff, Aj + (size_t)(w * 32 + it * 4) * 128);
        }
    }
    __syncthreads();   // drains vmcnt (global_load_lds)

    // ---- i-side B fragments from LDS (swizzled read), resident
    bf16x8 b[4][4];
    #pragma unroll
    for (int bt = 0; bt < 4; bt++)
        #pragma unroll
        for (int ks = 0; ks < 4; ks++)
            b[bt][ks] = *reinterpret_cast<const bf16x8*>(
                Ai + ((wi * 64 + bt * 16 + l15) * 16 + ((ks * 4 + l4) ^ (l15 & 7))) * 8);

    float dsum[4] = {0.f, 0.f, 0.f, 0.f};
    const float KE1 = 2.8853900817779268f;    // 2*log2(e)
    const float KE0 = -2.8853900817779268f;

    #pragma unroll
    for (int at = 0; at < 4; at++) {
        bf16x8 a[4];
        #pragma unroll
        for (int ks = 0; ks < 4; ks++)
            a[ks] = *reinterpret_cast<const bf16x8*>(
                Aj + ((wj * 64 + at * 16 + l15) * 16 + ((ks * 4 + l4) ^ (l15 & 7))) * 8);
        const int jt = jbase + wj * 64 + at * 16;

        #pragma unroll
        for (int bt = 0; bt < 4; bt++) {
            f32x4 acc = {0.f, 0.f, 0.f, 0.f};
            #pragma unroll
            for (int ks = 0; ks < 4; ks++)
                acc = __builtin_amdgcn_mfma_f32_16x16x32_bf16(a[ks], b[bt][ks], acc, 0, 0, 0);
            const bool dg = (jt == ibase + wi * 64 + bt * 16);   // tile holds diagonal
            #pragma unroll
            for (int q = 0; q < 4; q++) {
                float e = exp2f(fmaf(acc[q], KE1, KE0));         // exp(S_ij - 2)
                if (dg && (l15 == l4 * 4 + q)) e = 0.f;          // exclude j == i
                dsum[bt] += e;
            }
        }
    }

    // ---- collapse the 4 l4-groups (j-partition); i = l15 stays lane-local
    const int strip = jblk * 2 + wj;
    #pragma unroll
    for (int bt = 0; bt < 4; bt++) {
        float v0 = dsum[bt];
        v0 += __shfl_xor(v0, 16);
        v0 += __shfl_xor(v0, 32);
        if (l4 == 0)
            part[(ibase + wi * 64 + bt * 16 + l15) * 64 + strip] = v0;
    }
}

// K3: 256 blocks x 256 thr; wave = 4 rows. Strip reduce + rank-1 loss terms.
__global__ __launch_bounds__(256) void k_row(const __bf16* __restrict__ U,
                                             const long long* __restrict__ labels,
                                             const int* __restrict__ c1p,
                                             const float* __restrict__ part,
                                             const float* __restrict__ w1,
                                             const float* __restrict__ wall,
                                             float* __restrict__ rowC,
                                             float* __restrict__ rowU) {
    const int wid = threadIdx.x >> 6, lane = threadIdx.x & 63;
    const int c1 = *c1p;
    const float w1a = w1[2 * lane], w1b = w1[2 * lane + 1];
    const float wa  = wall[2 * lane], wb = wall[2 * lane + 1];
    float cs = 0.f, us = 0.f;
    #pragma unroll
    for (int rr = 0; rr < 4; rr++) {
        const int i = blockIdx.x * 16 + wid * 4 + rr;
        const int partner = (i < Bsz) ? i + Bsz : i - Bsz;
        float dn = part[i * 64 + lane];
        const float u0 = (float)U[(size_t)i * Dim + 2 * lane];
        const float u1 = (float)U[(size_t)i * Dim + 2 * lane + 1];
        const float p0 = (float)U[(size_t)partner * Dim + 2 * lane];
        const float p1 = (float)U[(size_t)partner * Dim + 2 * lane + 1];
        float d1 = u0 * w1a + u1 * w1b;   // u . w1
        float da = u0 * wa + u1 * wb;     // u . wall
        float ds = u0 * u0 + u1 * u1;     // u . u  (= S_ii / 2)
        float dp = u0 * p0 + u1 * p1;     // u . partner
        #pragma unroll
        for (int m = 1; m < 64; m <<= 1) {
            dn += __shfl_xor(dn, m);
            d1 += __shfl_xor(d1, m);
            da += __shfl_xor(da, m);
            ds += __shfl_xor(ds, m);
            dp += __shfl_xor(dp, m);
        }
        if (lane == 0) {
            const long long lb = labels[i & (Bsz - 1)];
            const float lnD = logf(dn) + 2.0f;            // lse over j != i (row max = 2)
            const float uns = lnD - 2.0f * dp;            // pos = S(i, partner)
            const float cnt = 2.f * (float)((lb == 1) ? c1 : (Bsz - c1));
            const float sii = 2.f * ds;
            const float sumeq = ((lb == 1) ? 2.f * d1 : 2.f * (da - d1)) - sii;
            const float sup = lnD - sumeq / (cnt - 1.f);
            cs += (lb == 1) ? sup : uns;
            us += uns;
        }
    }
    __shared__ float wcs[4], wus[4];
    if (lane == 0) { wcs[wid] = cs; wus[wid] = us; }
    __syncthreads();
    if (threadIdx.x == 0) {
        rowC[blockIdx.x] = wcs[0] + wcs[1] + wcs[2] + wcs[3];
        rowU[blockIdx.x] = wus[0] + wus[1] + wus[2] + wus[3];
    }
}

// K4: combine 256 block results -> scalar loss
__global__ __launch_bounds__(256) void k_comb(const float* __restrict__ rowC,
                                              const float* __restrict__ rowU,
                                              const int* __restrict__ c1p,
                                              float* __restrict__ out) {
    __shared__ float sc[256], su[256];
    const int t = threadIdx.x;
    sc[t] = rowC[t];
    su[t] = rowU[t];
    __syncthreads();
    for (int s = 128; s > 0; s >>= 1) {
        if (t < s) { sc[t] += sc[t + s]; su[t] += su[t + s]; }
        __syncthreads();
    }
    if (t == 0) out[0] = ((*c1p > 0) ? sc[0] : su[0]) / (float)Nrows;
}

extern "C" void kernel_launch(void* const* d_in, const int* in_sizes, int n_in,
                              void* d_out, int out_size, void* d_ws, size_t ws_size,
                              hipStream_t stream) {
    const float* z  = (const float*)d_in[0];
    const float* za = (const float*)d_in[1];
    const long long* labels = (const long long*)d_in[2];

    char* ws = (char*)d_ws;
    __bf16* U     = (__bf16*)(ws);
    float*  part  = (float*)(ws + (1u << 20));
    float*  w1p   = (float*)(ws + (2u << 20));
    float*  wallp = (float*)(ws + (2u << 20) + (128u << 10));
    float*  w1    = (float*)(ws + (2u << 20) + (256u << 10));
    float*  wall  = (float*)(ws + (2u << 20) + (256u << 10) + 512);
    int*    c1    = (int*)  (ws + (2u << 20) + (256u << 10) + 1024);
    float*  rowC  = (float*)(ws + (2u << 20) + (257u << 10));
    float*  rowU  = (float*)(ws + (2u << 20) + (258u << 10));
    float*  out   = (float*)d_out;

    hipLaunchKernelGGL(k_norm, dim3(256),  dim3(256), 0, stream, z, za, labels, U, w1p, wallp, c1);
    hipLaunchKernelGGL(k_gram, dim3(1025), dim3(256), 0, stream, U, w1p, wallp, part, w1, wall);
    hipLaunchKernelGGL(k_row,  dim3(256),  dim3(256), 0, stream, U, labels, c1, part, w1, wall, rowC, rowU);
    hipLaunchKernelGGL(k_comb, dim3(1),    dim3(256), 0, stream, rowC, rowU, c1, out);
}

// Round 11
// 32.046 us; speedup vs baseline: 1.1541x; 1.0681x over previous
//
#include <hip/hip_runtime.h>
#include <hip/hip_bf16.h>

#define Bsz 2048
#define Dim 128
#define Nrows 4096

typedef float f32x4 __attribute__((ext_vector_type(4)));
typedef __bf16 bf16x8 __attribute__((ext_vector_type(8)));

// ws layout:
//   U     @ 0           : 4096*128*2 = 1 MiB (bf16 normalized rows)
//   part  @ 1 MiB       : 4096*64*4  = 1 MiB (per (row,strip64) sum exp(S-2), diag excl)
//   w1p   @ 2 MiB       : 128 KiB (block partials of sum lab_j*u_j)
//   wallp @ 2 MiB+128K  : 128 KiB (block partials of sum u_j)
//   w1    @ 2 MiB+256K  : 512 B ; wall @ +512 B ; c1 @ +1 KiB
//   rowC  @ 2 MiB+257K  : 1 KiB ; rowU @ +1 KiB

// K1: normalize [z; z_aug] -> bf16 U; per-block partials of w1/wall; block 0: c1
__global__ __launch_bounds__(256) void k_norm(const float* __restrict__ z,
                                              const float* __restrict__ za,
                                              const long long* __restrict__ labels,
                                              __bf16* __restrict__ U,
                                              float* __restrict__ w1p,
                                              float* __restrict__ wallp,
                                              int* __restrict__ c1out) {
    const int wid = threadIdx.x >> 6, lane = threadIdx.x & 63;
    __shared__ float s1[4][128];
    __shared__ float s0[4][128];
    float a1x = 0.f, a1y = 0.f, a0x = 0.f, a0y = 0.f;
    #pragma unroll
    for (int pass = 0; pass < 4; pass++) {
        const int r = blockIdx.x * 16 + pass * 4 + wid;
        const float* src = (r < Bsz) ? (z + (size_t)r * Dim) : (za + (size_t)(r - Bsz) * Dim);
        float2 x = reinterpret_cast<const float2*>(src)[lane];
        float ss = x.x * x.x + x.y * x.y;
        #pragma unroll
        for (int m = 1; m < 64; m <<= 1) ss += __shfl_xor(ss, m);
        const float sc = 1.0f / fmaxf(sqrtf(ss), 1e-12f);
        const float u0 = x.x * sc, u1 = x.y * sc;
        __bf16* dst = U + (size_t)r * Dim + 2 * lane;
        dst[0] = (__bf16)u0;
        dst[1] = (__bf16)u1;
        const float lf = (labels[r & (Bsz - 1)] == 1) ? 1.f : 0.f;
        a0x += u0; a0y += u1;
        a1x = fmaf(lf, u0, a1x); a1y = fmaf(lf, u1, a1y);
    }
    s1[wid][2 * lane] = a1x; s1[wid][2 * lane + 1] = a1y;
    s0[wid][2 * lane] = a0x; s0[wid][2 * lane + 1] = a0y;
    __syncthreads();
    const int t = threadIdx.x;
    if (t < 128) {
        w1p[blockIdx.x * 128 + t]   = s1[0][t] + s1[1][t] + s1[2][t] + s1[3][t];
        wallp[blockIdx.x * 128 + t] = s0[0][t] + s0[1][t] + s0[2][t] + s0[3][t];
    }
    if (blockIdx.x == 0) {
        __shared__ int ci[256];
        int c = 0;
        #pragma unroll
        for (int k = 0; k < 8; k++) c += (int)labels[t * 8 + k];
        ci[t] = c;
        __syncthreads();
        for (int s = 128; s > 0; s >>= 1) {
            if (t < s) ci[t] += ci[t + s];
            __syncthreads();
        }
        if (t == 0) c1out[0] = ci[0];
    }
}

// K2: SYMMETRIC Gram. Blocks 1..528 = upper-triangle tiles (ib, jb>=ib), 128x128,
// R8's reg-staged both-panels LDS scheme (measured best). Swapped operands:
// e(i = bt*16+l15, j = at*16+l4*4+q). i-side sum: in-register + xor16/32.
// j-side sum (off-diag tiles only, symmetry): jq[q] over bt in-register, then
// 16-lane butterfly over l15. Diagonal excluded via cndmask in diag tiles.
// Block 0 reduces w1p/wallp -> w1/wall.
__global__ __launch_bounds__(256, 2) void k_gram(const __bf16* __restrict__ U,
                                                 const float* __restrict__ w1p,
                                                 const float* __restrict__ wallp,
                                                 float* __restrict__ part,
                                                 float* __restrict__ w1,
                                                 float* __restrict__ wall) {
    if (blockIdx.x == 0) {   // side block: reduce 256 w-partials -> w1/wall
        const int t = threadIdx.x;
        const int d = t & 127;
        const float* src = (t < 128) ? w1p : wallp;
        float acc = 0.f;
        #pragma unroll 8
        for (int k = 0; k < 256; k++) acc += src[k * 128 + d];
        if (t < 128) w1[d] = acc; else wall[d] = acc;
        return;
    }

    // triangular decode: block 1..528 -> (ib, jb), jb >= ib
    int bidx = blockIdx.x - 1, ib = 0;
    while (bidx >= 32 - ib) { bidx -= 32 - ib; ib++; }
    const int jb = ib + bidx;
    const bool diag = (ib == jb);

    __shared__ __bf16 Ai[128 * 128];
    __shared__ __bf16 Aj[128 * 128];
    const __bf16* AjP = diag ? Ai : Aj;

    const int ibase = ib * 128, jbase = jb * 128;
    const int w = threadIdx.x >> 6, lane = threadIdx.x & 63;
    const int wi = w & 1, wj = w >> 1;
    const int l15 = lane & 15, l4 = lane >> 4;

    // ---- stage panels (coalesced global reads; chunk-XOR swizzled LDS writes)
    {
        const int p = lane & 15, rsub = lane >> 4;
        #pragma unroll
        for (int it = 0; it < 8; it++) {
            const int rl = w * 32 + it * 4 + rsub;          // local row 0..127
            const int dst = (rl * 16 + (p ^ (rl & 7))) * 8;
            bf16x8 vi = *reinterpret_cast<const bf16x8*>(U + (size_t)(ibase + rl) * Dim + p * 8);
            *reinterpret_cast<bf16x8*>(Ai + dst) = vi;
            if (!diag) {
                bf16x8 vj = *reinterpret_cast<const bf16x8*>(U + (size_t)(jbase + rl) * Dim + p * 8);
                *reinterpret_cast<bf16x8*>(Aj + dst) = vj;
            }
        }
    }
    __syncthreads();

    // ---- i-side B fragments from LDS, resident
    bf16x8 b[4][4];
    #pragma unroll
    for (int bt = 0; bt < 4; bt++)
        #pragma unroll
        for (int ks = 0; ks < 4; ks++)
            b[bt][ks] = *reinterpret_cast<const bf16x8*>(
                Ai + ((wi * 64 + bt * 16 + l15) * 16 + ((ks * 4 + l4) ^ (l15 & 7))) * 8);

    float dsum[4] = {0.f, 0.f, 0.f, 0.f};
    const float KE1 = 2.8853900817779268f;    // 2*log2(e)
    const float KE0 = -2.8853900817779268f;
    const int stripI = ib * 2 + wi;

    #pragma unroll
    for (int at = 0; at < 4; at++) {
        bf16x8 a[4];
        #pragma unroll
        for (int ks = 0; ks < 4; ks++)
            a[ks] = *reinterpret_cast<const bf16x8*>(
                AjP + ((wj * 64 + at * 16 + l15) * 16 + ((ks * 4 + l4) ^ (l15 & 7))) * 8);
        const int jt = jbase + wj * 64 + at * 16;
        float jq[4] = {0.f, 0.f, 0.f, 0.f};

        #pragma unroll
        for (int bt = 0; bt < 4; bt++) {
            f32x4 acc = {0.f, 0.f, 0.f, 0.f};
            #pragma unroll
            for (int ks = 0; ks < 4; ks++)
                acc = __builtin_amdgcn_mfma_f32_16x16x32_bf16(a[ks], b[bt][ks], acc, 0, 0, 0);
            const bool dg = (jt == ibase + wi * 64 + bt * 16);   // holds diagonal
            #pragma unroll
            for (int q = 0; q < 4; q++) {
                float e = exp2f(fmaf(acc[q], KE1, KE0));         // exp(S_ij - 2)
                if (dg && (l15 == l4 * 4 + q)) e = 0.f;          // exclude j == i
                dsum[bt] += e;
                jq[q] += e;
            }
        }

        // j-side (symmetry): sum over the 64 local i's = over bt (done) + l15 lanes
        if (!diag) {
            #pragma unroll
            for (int q = 0; q < 4; q++) {
                float v = jq[q];
                v += __shfl_xor(v, 1);
                v += __shfl_xor(v, 2);
                v += __shfl_xor(v, 4);
                v += __shfl_xor(v, 8);
                jq[q] = v;
            }
            if (l15 == 0) {
                const int jgl = jbase + wj * 64 + at * 16 + l4 * 4;
                #pragma unroll
                for (int q = 0; q < 4; q++)
                    part[(jgl + q) * 64 + stripI] = jq[q];
            }
        }
    }

    // ---- i-side: collapse the 4 l4-groups; i = l15 stays lane-local
    const int stripJ = jb * 2 + wj;
    #pragma unroll
    for (int bt = 0; bt < 4; bt++) {
        float v0 = dsum[bt];
        v0 += __shfl_xor(v0, 16);
        v0 += __shfl_xor(v0, 32);
        if (l4 == 0)
            part[(ibase + wi * 64 + bt * 16 + l15) * 64 + stripJ] = v0;
    }
}

// K3: 256 blocks x 256 thr; wave = 4 rows. Strip reduce + rank-1 loss terms.
__global__ __launch_bounds__(256) void k_row(const __bf16* __restrict__ U,
                                             const long long* __restrict__ labels,
                                             const int* __restrict__ c1p,
                                             const float* __restrict__ part,
                                             const float* __restrict__ w1,
                                             const float* __restrict__ wall,
                                             float* __restrict__ rowC,
                                             float* __restrict__ rowU) {
    const int wid = threadIdx.x >> 6, lane = threadIdx.x & 63;
    const int c1 = *c1p;
    const float w1a = w1[2 * lane], w1b = w1[2 * lane + 1];
    const float wa  = wall[2 * lane], wb = wall[2 * lane + 1];
    float cs = 0.f, us = 0.f;
    #pragma unroll
    for (int rr = 0; rr < 4; rr++) {
        const int i = blockIdx.x * 16 + wid * 4 + rr;
        const int partner = (i < Bsz) ? i + Bsz : i - Bsz;
        float dn = part[i * 64 + lane];
        const float u0 = (float)U[(size_t)i * Dim + 2 * lane];
        const float u1 = (float)U[(size_t)i * Dim + 2 * lane + 1];
        const float p0 = (float)U[(size_t)partner * Dim + 2 * lane];
        const float p1 = (float)U[(size_t)partner * Dim + 2 * lane + 1];
        float d1 = u0 * w1a + u1 * w1b;   // u . w1
        float da = u0 * wa + u1 * wb;     // u . wall
        float ds = u0 * u0 + u1 * u1;     // u . u  (= S_ii / 2)
        float dp = u0 * p0 + u1 * p1;     // u . partner
        #pragma unroll
        for (int m = 1; m < 64; m <<= 1) {
            dn += __shfl_xor(dn, m);
            d1 += __shfl_xor(d1, m);
            da += __shfl_xor(da, m);
            ds += __shfl_xor(ds, m);
            dp += __shfl_xor(dp, m);
        }
        if (lane == 0) {
            const long long lb = labels[i & (Bsz - 1)];
            const float lnD = logf(dn) + 2.0f;            // lse over j != i (row max = 2)
            const float uns = lnD - 2.0f * dp;            // pos = S(i, partner)
            const float cnt = 2.f * (float)((lb == 1) ? c1 : (Bsz - c1));
            const float sii = 2.f * ds;
            const float sumeq = ((lb == 1) ? 2.f * d1 : 2.f * (da - d1)) - sii;
            const float sup = lnD - sumeq / (cnt - 1.f);
            cs += (lb == 1) ? sup : uns;
            us += uns;
        }
    }
    __shared__ float wcs[4], wus[4];
    if (lane == 0) { wcs[wid] = cs; wus[wid] = us; }
    __syncthreads();
    if (threadIdx.x == 0) {
        rowC[blockIdx.x] = wcs[0] + wcs[1] + wcs[2] + wcs[3];
        rowU[blockIdx.x] = wus[0] + wus[1] + wus[2] + wus[3];
    }
}

// K4: combine 256 block results -> scalar loss
__global__ __launch_bounds__(256) void k_comb(const float* __restrict__ rowC,
                                              const float* __restrict__ rowU,
                                              const int* __restrict__ c1p,
                                              float* __restrict__ out) {
    __shared__ float sc[256], su[256];
    const int t = threadIdx.x;
    sc[t] = rowC[t];
    su[t] = rowU[t];
    __syncthreads();
    for (int s = 128; s > 0; s >>= 1) {
        if (t < s) { sc[t] += sc[t + s]; su[t] += su[t + s]; }
        __syncthreads();
    }
    if (t == 0) out[0] = ((*c1p > 0) ? sc[0] : su[0]) / (float)Nrows;
}

extern "C" void kernel_launch(void* const* d_in, const int* in_sizes, int n_in,
                              void* d_out, int out_size, void* d_ws, size_t ws_size,
                              hipStream_t stream) {
    const float* z  = (const float*)d_in[0];
    const float* za = (const float*)d_in[1];
    const long long* labels = (const long long*)d_in[2];

    char* ws = (char*)d_ws;
    __bf16* U     = (__bf16*)(ws);
    float*  part  = (float*)(ws + (1u << 20));
    float*  w1p   = (float*)(ws + (2u << 20));
    float*  wallp = (float*)(ws + (2u << 20) + (128u << 10));
    float*  w1    = (float*)(ws + (2u << 20) + (256u << 10));
    float*  wall  = (float*)(ws + (2u << 20) + (256u << 10) + 512);
    int*    c1    = (int*)  (ws + (2u << 20) + (256u << 10) + 1024);
    float*  rowC  = (float*)(ws + (2u << 20) + (257u << 10));
    float*  rowU  = (float*)(ws + (2u << 20) + (258u << 10));
    float*  out   = (float*)d_out;

    hipLaunchKernelGGL(k_norm, dim3(256), dim3(256), 0, stream, z, za, labels, U, w1p, wallp, c1);
    hipLaunchKernelGGL(k_gram, dim3(529), dim3(256), 0, stream, U, w1p, wallp, part, w1, wall);
    hipLaunchKernelGGL(k_row,  dim3(256), dim3(256), 0, stream, U, labels, c1, part, w1, wall, rowC, rowU);
    hipLaunchKernelGGL(k_comb, dim3(1),   dim3(256), 0, stream, rowC, rowU, c1, out);
}

// Round 12
// 31.488 us; speedup vs baseline: 1.1746x; 1.0177x over previous
//
#include <hip/hip_runtime.h>
#include <hip/hip_bf16.h>

#define Bsz 2048
#define Dim 128
#define Nrows 4096

typedef float f32x4 __attribute__((ext_vector_type(4)));
typedef __bf16 bf16x8 __attribute__((ext_vector_type(8)));

// ws layout:
//   U     @ 0           : 4096*128*2 = 1 MiB (bf16 normalized rows)
//   part  @ 1 MiB       : 4096*64*4  = 1 MiB (per (row,strip64) sum exp(S-2), diag excl)
//   w1p   @ 2 MiB       : 128 KiB (block partials of sum lab_j*u_j)
//   wallp @ 2 MiB+128K  : 128 KiB (block partials of sum u_j)
//   w1    @ 2 MiB+256K  : 512 B ; wall @ +512 B ; c1 @ +1 KiB
//   rowC  @ 2 MiB+257K  : 1 KiB ; rowU @ +1 KiB

// K1: normalize [z; z_aug] -> bf16 U; per-block partials of w1/wall; block 0: c1
__global__ __launch_bounds__(256) void k_norm(const float* __restrict__ z,
                                              const float* __restrict__ za,
                                              const long long* __restrict__ labels,
                                              __bf16* __restrict__ U,
                                              float* __restrict__ w1p,
                                              float* __restrict__ wallp,
                                              int* __restrict__ c1out) {
    const int wid = threadIdx.x >> 6, lane = threadIdx.x & 63;
    __shared__ float s1[4][128];
    __shared__ float s0[4][128];
    float a1x = 0.f, a1y = 0.f, a0x = 0.f, a0y = 0.f;
    #pragma unroll
    for (int pass = 0; pass < 4; pass++) {
        const int r = blockIdx.x * 16 + pass * 4 + wid;
        const float* src = (r < Bsz) ? (z + (size_t)r * Dim) : (za + (size_t)(r - Bsz) * Dim);
        float2 x = reinterpret_cast<const float2*>(src)[lane];
        float ss = x.x * x.x + x.y * x.y;
        #pragma unroll
        for (int m = 1; m < 64; m <<= 1) ss += __shfl_xor(ss, m);
        const float sc = 1.0f / fmaxf(sqrtf(ss), 1e-12f);
        const float u0 = x.x * sc, u1 = x.y * sc;
        __bf16* dst = U + (size_t)r * Dim + 2 * lane;
        dst[0] = (__bf16)u0;
        dst[1] = (__bf16)u1;
        const float lf = (labels[r & (Bsz - 1)] == 1) ? 1.f : 0.f;
        a0x += u0; a0y += u1;
        a1x = fmaf(lf, u0, a1x); a1y = fmaf(lf, u1, a1y);
    }
    s1[wid][2 * lane] = a1x; s1[wid][2 * lane + 1] = a1y;
    s0[wid][2 * lane] = a0x; s0[wid][2 * lane + 1] = a0y;
    __syncthreads();
    const int t = threadIdx.x;
    if (t < 128) {
        w1p[blockIdx.x * 128 + t]   = s1[0][t] + s1[1][t] + s1[2][t] + s1[3][t];
        wallp[blockIdx.x * 128 + t] = s0[0][t] + s0[1][t] + s0[2][t] + s0[3][t];
    }
    if (blockIdx.x == 0) {
        __shared__ int ci[256];
        int c = 0;
        #pragma unroll
        for (int k = 0; k < 8; k++) c += (int)labels[t * 8 + k];
        ci[t] = c;
        __syncthreads();
        for (int s = 128; s > 0; s >>= 1) {
            if (t < s) ci[t] += ci[t + s];
            __syncthreads();
        }
        if (t == 0) c1out[0] = ci[0];
    }
}

// K2: pipelined Gram. Blocks 1..512: (ib = 0..31, jc = 0..15), 128 i-rows x
// 256 j-cols = TWO 128x128 j-tiles, double-buffered LDS (2x32 KB, 2 blocks/CU).
// i-side b-frags: direct global regs, loaded once per block (amortized 2x,
// latency under j0 staging). j1 loads issued BEFORE compute(j0) (T14 split) so
// the second barrier's vmcnt drain is free. Swapped operands: i = l15
// lane-local -> scalar dsum; 2 shuffles per bt. Block 0 reduces w1p/wallp.
__global__ __launch_bounds__(256, 2) void k_gram(const __bf16* __restrict__ U,
                                                 const float* __restrict__ w1p,
                                                 const float* __restrict__ wallp,
                                                 float* __restrict__ part,
                                                 float* __restrict__ w1,
                                                 float* __restrict__ wall) {
    if (blockIdx.x == 0) {   // side block: reduce 256 w-partials -> w1/wall
        const int t = threadIdx.x;
        const int d = t & 127;
        const float* src = (t < 128) ? w1p : wallp;
        float acc = 0.f;
        #pragma unroll 8
        for (int k = 0; k < 256; k++) acc += src[k * 128 + d];
        if (t < 128) w1[d] = acc; else wall[d] = acc;
        return;
    }

    __shared__ __bf16 Aj0[128 * 128];
    __shared__ __bf16 Aj1[128 * 128];

    const int ib = (blockIdx.x - 1) >> 4;     // 0..31
    const int jc = (blockIdx.x - 1) & 15;     // 0..15
    const int ibase = ib * 128;
    const int jbase0 = jc * 256, jbase1 = jc * 256 + 128;
    const int w = threadIdx.x >> 6, lane = threadIdx.x & 63;
    const int wi = w & 1, wj = w >> 1;
    const int l15 = lane & 15, l4 = lane >> 4;
    const int p = lane & 15, rsub = lane >> 4;

    // ---- i-side b-frags: direct global, once per block (first: longest dep chain)
    bf16x8 b[4][4];
    #pragma unroll
    for (int bt = 0; bt < 4; bt++)
        #pragma unroll
        for (int ks = 0; ks < 4; ks++)
            b[bt][ks] = *reinterpret_cast<const bf16x8*>(
                U + (size_t)(ibase + wi * 64 + bt * 16 + l15) * Dim + (ks * 4 + l4) * 8);

    // ---- stage j0 (reg -> swizzled LDS write)
    {
        bf16x8 st[8];
        #pragma unroll
        for (int it = 0; it < 8; it++) {
            const int rl = w * 32 + it * 4 + rsub;
            st[it] = *reinterpret_cast<const bf16x8*>(U + (size_t)(jbase0 + rl) * Dim + p * 8);
        }
        #pragma unroll
        for (int it = 0; it < 8; it++) {
            const int rl = w * 32 + it * 4 + rsub;
            *reinterpret_cast<bf16x8*>(Aj0 + (rl * 16 + (p ^ (rl & 7))) * 8) = st[it];
        }
    }
    __syncthreads();

    // ---- issue j1 loads NOW (latency hides under compute j0)
    bf16x8 st1[8];
    #pragma unroll
    for (int it = 0; it < 8; it++) {
        const int rl = w * 32 + it * 4 + rsub;
        st1[it] = *reinterpret_cast<const bf16x8*>(U + (size_t)(jbase1 + rl) * Dim + p * 8);
    }

    const float KE1 = 2.8853900817779268f;    // 2*log2(e)
    const float KE0 = -2.8853900817779268f;

    auto compute = [&](const __bf16* Aj, int jbase, int strip) {
        float dsum[4] = {0.f, 0.f, 0.f, 0.f};
        #pragma unroll
        for (int at = 0; at < 4; at++) {
            bf16x8 a[4];
            #pragma unroll
            for (int ks = 0; ks < 4; ks++)
                a[ks] = *reinterpret_cast<const bf16x8*>(
                    Aj + ((wj * 64 + at * 16 + l15) * 16 + ((ks * 4 + l4) ^ (l15 & 7))) * 8);
            const int jt = jbase + wj * 64 + at * 16;
            #pragma unroll
            for (int bt = 0; bt < 4; bt++) {
                f32x4 acc = {0.f, 0.f, 0.f, 0.f};
                #pragma unroll
                for (int ks = 0; ks < 4; ks++)
                    acc = __builtin_amdgcn_mfma_f32_16x16x32_bf16(a[ks], b[bt][ks], acc, 0, 0, 0);
                const bool dg = (jt == ibase + wi * 64 + bt * 16);   // holds diagonal
                #pragma unroll
                for (int q = 0; q < 4; q++) {
                    float e = exp2f(fmaf(acc[q], KE1, KE0));         // exp(S_ij - 2)
                    if (dg && (l15 == l4 * 4 + q)) e = 0.f;          // exclude j == i
                    dsum[bt] += e;
                }
            }
        }
        #pragma unroll
        for (int bt = 0; bt < 4; bt++) {
            float v0 = dsum[bt];
            v0 += __shfl_xor(v0, 16);
            v0 += __shfl_xor(v0, 32);
            if (l4 == 0)
                part[(ibase + wi * 64 + bt * 16 + l15) * 64 + strip] = v0;
        }
    };

    // ---- compute tile 0
    compute(Aj0, jbase0, jc * 4 + wj);

    // ---- write j1 (separate buffer: no pre-barrier needed), then one barrier
    #pragma unroll
    for (int it = 0; it < 8; it++) {
        const int rl = w * 32 + it * 4 + rsub;
        *reinterpret_cast<bf16x8*>(Aj1 + (rl * 16 + (p ^ (rl & 7))) * 8) = st1[it];
    }
    __syncthreads();

    // ---- compute tile 1
    compute(Aj1, jbase1, jc * 4 + 2 + wj);
}

// K3: 256 blocks x 256 thr; wave = 4 rows. Strip reduce + rank-1 loss terms.
__global__ __launch_bounds__(256) void k_row(const __bf16* __restrict__ U,
                                             const long long* __restrict__ labels,
                                             const int* __restrict__ c1p,
                                             const float* __restrict__ part,
                                             const float* __restrict__ w1,
                                             const float* __restrict__ wall,
                                             float* __restrict__ rowC,
                                             float* __restrict__ rowU) {
    const int wid = threadIdx.x >> 6, lane = threadIdx.x & 63;
    const int c1 = *c1p;
    const float w1a = w1[2 * lane], w1b = w1[2 * lane + 1];
    const float wa  = wall[2 * lane], wb = wall[2 * lane + 1];
    float cs = 0.f, us = 0.f;
    #pragma unroll
    for (int rr = 0; rr < 4; rr++) {
        const int i = blockIdx.x * 16 + wid * 4 + rr;
        const int partner = (i < Bsz) ? i + Bsz : i - Bsz;
        float dn = part[i * 64 + lane];
        const float u0 = (float)U[(size_t)i * Dim + 2 * lane];
        const float u1 = (float)U[(size_t)i * Dim + 2 * lane + 1];
        const float p0 = (float)U[(size_t)partner * Dim + 2 * lane];
        const float p1 = (float)U[(size_t)partner * Dim + 2 * lane + 1];
        float d1 = u0 * w1a + u1 * w1b;   // u . w1
        float da = u0 * wa + u1 * wb;     // u . wall
        float ds = u0 * u0 + u1 * u1;     // u . u  (= S_ii / 2)
        float dp = u0 * p0 + u1 * p1;     // u . partner
        #pragma unroll
        for (int m = 1; m < 64; m <<= 1) {
            dn += __shfl_xor(dn, m);
            d1 += __shfl_xor(d1, m);
            da += __shfl_xor(da, m);
            ds += __shfl_xor(ds, m);
            dp += __shfl_xor(dp, m);
        }
        if (lane == 0) {
            const long long lb = labels[i & (Bsz - 1)];
            const float lnD = logf(dn) + 2.0f;            // lse over j != i (row max = 2)
            const float uns = lnD - 2.0f * dp;            // pos = S(i, partner)
            const float cnt = 2.f * (float)((lb == 1) ? c1 : (Bsz - c1));
            const float sii = 2.f * ds;
            const float sumeq = ((lb == 1) ? 2.f * d1 : 2.f * (da - d1)) - sii;
            const float sup = lnD - sumeq / (cnt - 1.f);
            cs += (lb == 1) ? sup : uns;
            us += uns;
        }
    }
    __shared__ float wcs[4], wus[4];
    if (lane == 0) { wcs[wid] = cs; wus[wid] = us; }
    __syncthreads();
    if (threadIdx.x == 0) {
        rowC[blockIdx.x] = wcs[0] + wcs[1] + wcs[2] + wcs[3];
        rowU[blockIdx.x] = wus[0] + wus[1] + wus[2] + wus[3];
    }
}

// K4: combine 256 block results -> scalar loss
__global__ __launch_bounds__(256) void k_comb(const float* __restrict__ rowC,
                                              const float* __restrict__ rowU,
                                              const int* __restrict__ c1p,
                                              float* __restrict__ out) {
    __shared__ float sc[256], su[256];
    const int t = threadIdx.x;
    sc[t] = rowC[t];
    su[t] = rowU[t];
    __syncthreads();
    for (int s = 128; s > 0; s >>= 1) {
        if (t < s) { sc[t] += sc[t + s]; su[t] += su[t + s]; }
        __syncthreads();
    }
    if (t == 0) out[0] = ((*c1p > 0) ? sc[0] : su[0]) / (float)Nrows;
}

extern "C" void kernel_launch(void* const* d_in, const int* in_sizes, int n_in,
                              void* d_out, int out_size, void* d_ws, size_t ws_size,
                              hipStream_t stream) {
    const float* z  = (const float*)d_in[0];
    const float* za = (const float*)d_in[1];
    const long long* labels = (const long long*)d_in[2];

    char* ws = (char*)d_ws;
    __bf16* U     = (__bf16*)(ws);
    float*  part  = (float*)(ws + (1u << 20));
    float*  w1p   = (float*)(ws + (2u << 20));
    float*  wallp = (float*)(ws + (2u << 20) + (128u << 10));
    float*  w1    = (float*)(ws + (2u << 20) + (256u << 10));
    float*  wall  = (float*)(ws + (2u << 20) + (256u << 10) + 512);
    int*    c1    = (int*)  (ws + (2u << 20) + (256u << 10) + 1024);
    float*  rowC  = (float*)(ws + (2u << 20) + (257u << 10));
    float*  rowU  = (float*)(ws + (2u << 20) + (258u << 10));
    float*  out   = (float*)d_out;

    hipLaunchKernelGGL(k_norm, dim3(256), dim3(256), 0, stream, z, za, labels, U, w1p, wallp, c1);
    hipLaunchKernelGGL(k_gram, dim3(513), dim3(256), 0, stream, U, w1p, wallp, part, w1, wall);
    hipLaunchKernelGGL(k_row,  dim3(256), dim3(256), 0, stream, U, labels, c1, part, w1, wall, rowC, rowU);
    hipLaunchKernelGGL(k_comb, dim3(1),   dim3(256), 0, stream, rowC, rowU, c1, out);
}